// Round 6
// baseline (157.068 us; speedup 1.0000x reference)
//
#include <hip/hip_runtime.h>
#include <cstdint>

#define NN 2048
#define LOG2E 1.4426950408889634f

typedef __attribute__((ext_vector_type(8))) short bf16x8;
typedef __attribute__((ext_vector_type(4))) float f32x4;

__device__ __forceinline__ unsigned short f2bf(float x){
  union { float f; unsigned u; } v; v.f = x;
  unsigned r = v.u + 0x7FFFu + ((v.u >> 16) & 1u);
  return (unsigned short)(r >> 16);
}
__device__ __forceinline__ unsigned pack2(float a, float b){
  return (unsigned)f2bf(a) | ((unsigned)f2bf(b) << 16);
}
// pack two already-truncated uints (value & 0xFFFF0000) in one v_perm
__device__ __forceinline__ unsigned permpack(unsigned hi, unsigned lo){
  return __builtin_amdgcn_perm(hi, lo, 0x07060302u);
}

// ---------------- K0: adj->bitmask (blocks 0..2047) + W^T bf16 (blocks 2048..2303) ----------------
__global__ __launch_bounds__(256) void k_prep(const float* __restrict__ adj,
                                              const float* __restrict__ W,
                                              unsigned long long* __restrict__ ab,
                                              unsigned short* __restrict__ Wt){
  int tid = threadIdx.x;
  if (blockIdx.x < 2048){
    int i = blockIdx.x;
    int w = tid >> 6, lane = tid & 63;
    #pragma unroll
    for (int seg = 0; seg < 8; seg++){
      int j = seg * 256 + tid;
      unsigned long long m = __ballot(adj[(size_t)i * NN + j] != 0.0f);
      if (lane == 0) ab[i * 32 + seg * 4 + w] = m;
    }
  } else {
    int g = (blockIdx.x - 2048) * 256 + tid;   // g = o*256 + k
    int o = g >> 8, k = g & 255;
    Wt[g] = f2bf(W[k * 256 + o]);
  }
}

// ---------------- K1: fused Wh=h@W -> s1,s2 (log2e-scaled) + WhT(bf16) ----------------
// grid 512 (32 global rows each => 2 blocks/CU), 256 threads (4 waves).
// BM=32, BO=256 (wave owns 64 cols), BK=64; double-buffered As (static idx),
// direct-from-global B frags double-buffered.
__global__ __launch_bounds__(256, 2) void k_fused_gemm(const float* __restrict__ h,
                                                       const unsigned short* __restrict__ Wt,
                                                       const float* __restrict__ a,
                                                       unsigned short* __restrict__ WhT,
                                                       float* __restrict__ s1c,
                                                       float* __restrict__ s2c){
  __shared__ __align__(16) unsigned short As[2][32 * 72];  //  9216 B
  __shared__ __align__(16) unsigned short Ts[256 * 40];    // 20480 B (o-major, 32 i + 8 pad)
  __shared__ float s1p[4][32], s2p[4][32];                 //  1024 B
  const int tid = threadIdx.x;
  const int r0 = blockIdx.x * 32;            // global row over B*N
  const int b  = r0 >> 11;
  const int i0 = r0 & (NN - 1);
  const int w = tid >> 6, lane = tid & 63, lhi = lane >> 4, llo = lane & 15;
  const int wc = w * 64;

  f32x4 acc[2][4];
  #pragma unroll
  for (int i = 0; i < 2; i++)
    #pragma unroll
    for (int j = 0; j < 4; j++){ acc[i][j][0]=0.f; acc[i][j][1]=0.f; acc[i][j][2]=0.f; acc[i][j][3]=0.f; }

  const int ar = tid >> 3;            // A staging row 0..31
  const int as_ = (tid & 7) * 8;      // 8-float segment

  // prefetch ALL of this block's h (8 x float4 in flight)
  float4 hv[4][2];
  #pragma unroll
  for (int t = 0; t < 4; t++){
    const float* hp = h + (size_t)(r0 + ar) * 256 + t * 64 + as_;
    hv[t][0] = *(const float4*)hp;
    hv[t][1] = *(const float4*)(hp + 4);
  }

  auto loadB = [&](int k0, bf16x8* dst){
    #pragma unroll
    for (int ot = 0; ot < 4; ot++)
      #pragma unroll
      for (int kk = 0; kk < 2; kk++)
        dst[ot * 2 + kk] = *(const bf16x8*)(Wt + (size_t)(wc + ot * 16 + llo) * 256 + k0 + kk * 32 + lhi * 8);
  };

  bf16x8 bfr[2][8];
  loadB(0, bfr[0]);

  #pragma unroll
  for (int t = 0; t < 4; t++){
    uint4 q = make_uint4(pack2(hv[t][0].x, hv[t][0].y), pack2(hv[t][0].z, hv[t][0].w),
                         pack2(hv[t][1].x, hv[t][1].y), pack2(hv[t][1].z, hv[t][1].w));
    if (t) __syncthreads();
    *(uint4*)&As[t & 1][ar * 72 + as_] = q;
    __syncthreads();
    if (t < 3) loadB((t + 1) * 64, bfr[(t + 1) & 1]);
    bf16x8 af[2][2];
    #pragma unroll
    for (int kk = 0; kk < 2; kk++)
      #pragma unroll
      for (int it = 0; it < 2; it++)
        af[kk][it] = *(const bf16x8*)&As[t & 1][(it * 16 + llo) * 72 + kk * 32 + lhi * 8];
    #pragma unroll
    for (int kk = 0; kk < 2; kk++)
      #pragma unroll
      for (int it = 0; it < 2; it++)
        #pragma unroll
        for (int ot = 0; ot < 4; ot++)
          acc[it][ot] = __builtin_amdgcn_mfma_f32_16x16x32_bf16(af[kk][it], bfr[t & 1][ot * 2 + kk], acc[it][ot], 0, 0, 0);
  }

  // ---- epilogue 1: s1/s2 partial dots (log2e folded) ----
  float a1v[4], a2v[4];
  #pragma unroll
  for (int ot = 0; ot < 4; ot++){
    a1v[ot] = a[wc + ot * 16 + llo] * LOG2E;
    a2v[ot] = a[256 + wc + ot * 16 + llo] * LOG2E;
  }
  #pragma unroll
  for (int it = 0; it < 2; it++){
    #pragma unroll
    for (int q = 0; q < 4; q++){
      float p1 = 0.f, p2 = 0.f;
      #pragma unroll
      for (int ot = 0; ot < 4; ot++){
        p1 += acc[it][ot][q] * a1v[ot];
        p2 += acc[it][ot][q] * a2v[ot];
      }
      #pragma unroll
      for (int o = 1; o < 16; o <<= 1){ p1 += __shfl_xor(p1, o); p2 += __shfl_xor(p2, o); }
      if (llo == 0){
        s1p[w][it * 16 + lhi * 4 + q] = p1;
        s2p[w][it * 16 + lhi * 4 + q] = p2;
      }
    }
  }

  // ---- epilogue 2: transpose acc (bf16, round) into Ts[o][i_local] ----
  #pragma unroll
  for (int it = 0; it < 2; it++){
    #pragma unroll
    for (int ot = 0; ot < 4; ot++){
      int o = wc + ot * 16 + llo;
      uint2 u = make_uint2(pack2(acc[it][ot][0], acc[it][ot][1]),
                           pack2(acc[it][ot][2], acc[it][ot][3]));
      *(uint2*)&Ts[o * 40 + it * 16 + lhi * 4] = u;
    }
  }
  __syncthreads();

  if (tid < 32){
    float t1 = 0.f, t2 = 0.f;
    #pragma unroll
    for (int g = 0; g < 4; g++){ t1 += s1p[g][tid]; t2 += s2p[g][tid]; }
    s1c[r0 + tid] = t1;
    s2c[r0 + tid] = t2;
  }
  #pragma unroll
  for (int p = 0; p < 4; p++){
    int o = p * 64 + (tid >> 2), col = (tid & 3) * 8;
    *(uint4*)(WhT + (size_t)(b * 256 + o) * 2048 + i0 + col) = *(const uint4*)&Ts[o * 40 + col];
  }
}

// ---------------- K2: h' = softmax(P) @ Wh ----------------
// grid 1024 (b=bid&7 XCD-affine; 4 blocks/CU), 256 threads (4 waves).
// BM=32, BO=128 (wave owns 32 cols), BK=64. One barrier per stage; double-buffered
// Ps with STATIC buffer indices; P(t+1) VALU overlaps MFMA(t).
__global__ __launch_bounds__(256, 4) void k_attn(const float* __restrict__ s1c,
                                                 const float* __restrict__ s2c,
                                                 const unsigned short* __restrict__ WhT,
                                                 const unsigned long long* __restrict__ ab,
                                                 float* __restrict__ out){
  __shared__ __align__(16) float s2s[2048];                  //  8192 B
  __shared__ __align__(16) unsigned short Ps[2][32 * 72];    //  9216 B
  __shared__ __align__(16) unsigned char bitsB[32 * 264];    //  8448 B
  __shared__ float s1s[32], lin[32], red[4];
  const int tid = threadIdx.x;
  const int bid = blockIdx.x;
  const int b = bid & 7;
  const int r = bid >> 3;                    // 0..127
  const int i0 = (r & 63) * 32;
  const int o0 = (r >> 6) * 128;
  const int w = tid >> 6, lane = tid & 63, lhi = lane >> 4, llo = lane & 15;
  const int co = o0 + w * 32;                // wave's col base

  // ---- preamble staging: s2 row-space (+max), s1 tile, adjacency bitmask rows ----
  float4 v0 = ((const float4*)(s2c + (size_t)b * NN))[tid];
  float4 v1 = ((const float4*)(s2c + (size_t)b * NN))[tid + 256];
  ((float4*)s2s)[tid]       = v0;
  ((float4*)s2s)[tid + 256] = v1;
  float vmax = fmaxf(fmaxf(fmaxf(v0.x, v0.y), fmaxf(v0.z, v0.w)),
                     fmaxf(fmaxf(v1.x, v1.y), fmaxf(v1.z, v1.w)));
  #pragma unroll
  for (int o = 32; o; o >>= 1) vmax = fmaxf(vmax, __shfl_xor(vmax, o));
  if (lane == 0) red[w] = vmax;
  if (tid < 32) s1s[tid] = s1c[(size_t)b * NN + i0 + tid];
  // stage 32 rows x 32 u64 mask words, row stride 264 B
  #pragma unroll
  for (int k = 0; k < 4; k++){
    int g = k * 256 + tid;                 // 0..1023
    unsigned long long mw = ab[(size_t)i0 * 32 + g];
    *(unsigned long long*)&bitsB[(g >> 5) * 264 + (g & 31) * 8] = mw;
  }
  __syncthreads();
  float m2 = fmaxf(fmaxf(red[0], red[1]), fmaxf(red[2], red[3]));

  const int pi = tid >> 3;                   // P row 0..31
  const int e8 = tid & 7;                    // j-subgroup
  const int pj = e8 * 8;                     // 8 j's per thread
  const float s1v = s1s[pi];
  const float xm = s1v + m2;
  const float mv = fmaxf(xm, 0.2f * xm);     // upper bound on row max (lrelu monotone)
  const float c1 = s1v - mv;                 // y = max(s2+c1, 0.2*s2+c2)
  const float c2 = 0.2f * s1v - mv;
  float rs = 0.f;

  f32x4 acc[2][2];
  #pragma unroll
  for (int i = 0; i < 2; i++)
    #pragma unroll
    for (int j = 0; j < 2; j++){ acc[i][j][0]=0.f; acc[i][j][1]=0.f; acc[i][j][2]=0.f; acc[i][j][3]=0.f; }

  auto loadB = [&](int j0, bf16x8* dst){
    #pragma unroll
    for (int ot = 0; ot < 2; ot++)
      #pragma unroll
      for (int kk = 0; kk < 2; kk++)
        dst[ot * 2 + kk] = *(const bf16x8*)(WhT + (size_t)(b * 256 + co + ot * 16 + llo) * 2048 + j0 + kk * 32 + lhi * 8);
  };

  unsigned pu[8];
  auto computeP = [&](int tn){
    unsigned bits = bitsB[pi * 264 + tn * 8 + e8];
    const float* sp = &s2s[tn * 64 + pj];
    float4 xa = *(const float4*)sp;
    float4 xb = *(const float4*)(sp + 4);
    float xs[8] = {xa.x, xa.y, xa.z, xa.w, xb.x, xb.y, xb.z, xb.w};
    #pragma unroll
    for (int e = 0; e < 8; e++){
      float s2v = xs[e];
      float y = fmaxf(s2v + c1, __builtin_fmaf(0.2f, s2v, c2));
      float p = __builtin_amdgcn_exp2f(y);
      unsigned m = ((bits >> e) & 1u) ? 0xFFFF0000u : 0u;
      unsigned u = __float_as_uint(p) & m;
      rs += __uint_as_float(u);
      pu[e] = u;
    }
  };

  // stage body with compile-time buffer selector and static B-frag arrays
  auto stageBody = [&](int t, int BUF, bf16x8* curB, bf16x8* nxtB, bool last){
    uint4 q = make_uint4(permpack(pu[1], pu[0]), permpack(pu[3], pu[2]),
                         permpack(pu[5], pu[4]), permpack(pu[7], pu[6]));
    *(uint4*)&Ps[BUF][pi * 72 + pj] = q;
    __syncthreads();
    if (!last) loadB((t + 1) * 64, nxtB);
    bf16x8 af[2][2];
    #pragma unroll
    for (int kk = 0; kk < 2; kk++)
      #pragma unroll
      for (int it = 0; it < 2; it++)
        af[kk][it] = *(const bf16x8*)&Ps[BUF][(it * 16 + llo) * 72 + kk * 32 + lhi * 8];
    if (!last) computeP(t + 1);              // VALU overlaps MFMA below
    #pragma unroll
    for (int kk = 0; kk < 2; kk++)
      #pragma unroll
      for (int it = 0; it < 2; it++)
        #pragma unroll
        for (int ot = 0; ot < 2; ot++)
          acc[it][ot] = __builtin_amdgcn_mfma_f32_16x16x32_bf16(af[kk][it], curB[ot * 2 + kk], acc[it][ot], 0, 0, 0);
  };

  bf16x8 bA[4], bB[4];
  loadB(0, bA);
  computeP(0);
  for (int t2 = 0; t2 < 32; t2 += 2){
    stageBody(t2,     0, bA, bB, false);
    stageBody(t2 + 1, 1, bB, bA, t2 + 1 == 31);
  }

  // ---- row sums -> 1/l ----
  rs += __shfl_xor(rs, 1);
  rs += __shfl_xor(rs, 2);
  rs += __shfl_xor(rs, 4);
  if (e8 == 0) lin[pi] = 1.0f / rs;
  __syncthreads();

  // ---- epilogue: scale + store ----
  #pragma unroll
  for (int it = 0; it < 2; it++){
    #pragma unroll
    for (int ot = 0; ot < 2; ot++){
      int col = co + ot * 16 + llo;
      #pragma unroll
      for (int q = 0; q < 4; q++){
        int row = it * 16 + lhi * 4 + q;
        out[(size_t)(b * NN + i0 + row) * 256 + col] = acc[it][ot][q] * lin[row];
      }
    }
  }
}

extern "C" void kernel_launch(void* const* d_in, const int* in_sizes, int n_in,
                              void* d_out, int out_size, void* d_ws, size_t ws_size,
                              hipStream_t stream) {
  const float* h   = (const float*)d_in[0];
  const float* adj = (const float*)d_in[1];
  const float* W   = (const float*)d_in[2];
  const float* a   = (const float*)d_in[3];
  float* out = (float*)d_out;

  char* ws = (char*)d_ws;
  unsigned short* WhT      = (unsigned short*)(ws);                 // 8,388,608 B
  unsigned short* Wt       = (unsigned short*)(ws + 8388608);       //   131,072 B
  unsigned long long* ab   = (unsigned long long*)(ws + 8519680);   //   524,288 B
  float* s1c               = (float*)(ws + 9043968);                //    65,536 B
  float* s2c               = (float*)(ws + 9109504);                //    65,536 B

  hipLaunchKernelGGL(k_prep,       dim3(2304), dim3(256), 0, stream, adj, W, ab, Wt);
  hipLaunchKernelGGL(k_fused_gemm, dim3(512),  dim3(256), 0, stream, h, Wt, a, WhT, s1c, s2c);
  hipLaunchKernelGGL(k_attn,       dim3(1024), dim3(256), 0, stream, s1c, s2c, WhT, ab, out);
}

// Round 8
// 134.401 us; speedup vs baseline: 1.1687x; 1.1687x over previous
//
#include <hip/hip_runtime.h>
#include <cstdint>

#define NN 2048
#define LOG2E 1.4426950408889634f

typedef __attribute__((ext_vector_type(8))) short bf16x8;
typedef __attribute__((ext_vector_type(4))) float f32x4;

__device__ __forceinline__ unsigned short f2bf(float x){
  union { float f; unsigned u; } v; v.f = x;
  unsigned r = v.u + 0x7FFFu + ((v.u >> 16) & 1u);
  return (unsigned short)(r >> 16);
}
__device__ __forceinline__ unsigned pack2(float a, float b){
  return (unsigned)f2bf(a) | ((unsigned)f2bf(b) << 16);
}
// pack two already-truncated uints (value & 0xFFFF0000) in one v_perm
__device__ __forceinline__ unsigned permpack(unsigned hi, unsigned lo){
  return __builtin_amdgcn_perm(hi, lo, 0x07060302u);
}

// ---------------- K0: adj->bitmask (blocks 0..2047) + W^T bf16 (blocks 2048..2303) ----------------
__global__ __launch_bounds__(256) void k_prep(const float* __restrict__ adj,
                                              const float* __restrict__ W,
                                              unsigned long long* __restrict__ ab,
                                              unsigned short* __restrict__ Wt){
  int tid = threadIdx.x;
  if (blockIdx.x < 2048){
    int i = blockIdx.x;
    int w = tid >> 6, lane = tid & 63;
    #pragma unroll
    for (int seg = 0; seg < 8; seg++){
      int j = seg * 256 + tid;
      unsigned long long m = __ballot(adj[(size_t)i * NN + j] != 0.0f);
      if (lane == 0) ab[i * 32 + seg * 4 + w] = m;
    }
  } else {
    int g = (blockIdx.x - 2048) * 256 + tid;   // g = o*256 + k
    int o = g >> 8, k = g & 255;
    Wt[g] = f2bf(W[k * 256 + o]);
  }
}

// ---------------- K1: fused Wh=h@W -> s1,s2 (log2e-scaled) + WhT(bf16) ----------------
// grid 256, 512 threads (8 waves). BM=64, BO=256 (wave owns 32 cols), BK=64.
// FRAG-LINEAR As: wave w stages A-fragment f=w (it=w>>1, kk=w&1); LDS writes and
// reads are lane-linear ds_*_b128 => conflict-free. One barrier per stage.
__global__ __launch_bounds__(512, 2) void k_fused_gemm(const float* __restrict__ h,
                                                       const unsigned short* __restrict__ Wt,
                                                       const float* __restrict__ a,
                                                       unsigned short* __restrict__ WhT,
                                                       float* __restrict__ s1c,
                                                       float* __restrict__ s2c){
  __shared__ __align__(16) unsigned char As[2 * 8192];     // 2 bufs x 8 frags x 1 KB
  __shared__ __align__(16) unsigned short Ts[256 * 72];    // 36864 B
  __shared__ float s1p[8][64], s2p[8][64];                 //  4096 B
  const int tid = threadIdx.x;
  const int r0 = blockIdx.x * 64;
  const int b  = r0 >> 11;
  const int i0 = r0 & (NN - 1);
  const int w = tid >> 6, lane = tid & 63, lhi = lane >> 4, llo = lane & 15;
  const int wc = w * 32;
  const int sit = w >> 1, skk = w & 1;          // staging role: frag (sit,skk)
  const int srow = sit * 16 + llo;              // A row this thread stages
  const int skol = skk * 32 + lhi * 8;          // A col segment

  f32x4 acc[4][2];
  #pragma unroll
  for (int i = 0; i < 4; i++)
    #pragma unroll
    for (int j = 0; j < 2; j++){ acc[i][j][0]=0.f; acc[i][j][1]=0.f; acc[i][j][2]=0.f; acc[i][j][3]=0.f; }

  // prefetch all 4 k-tiles of this thread's A-frag slice
  float4 hv[4][2];
  #pragma unroll
  for (int t = 0; t < 4; t++){
    const float* hp = h + (size_t)(r0 + srow) * 256 + t * 64 + skol;
    hv[t][0] = *(const float4*)hp;
    hv[t][1] = *(const float4*)(hp + 4);
  }

  auto loadB = [&](int k0, bf16x8* dst){
    #pragma unroll
    for (int ot = 0; ot < 2; ot++)
      #pragma unroll
      for (int kk = 0; kk < 2; kk++)
        dst[ot * 2 + kk] = *(const bf16x8*)(Wt + (size_t)(wc + ot * 16 + llo) * 256 + k0 + kk * 32 + lhi * 8);
  };
  bf16x8 bfr[2][4];
  loadB(0, bfr[0]);

  #pragma unroll
  for (int t = 0; t < 4; t++){
    uint4 q = make_uint4(pack2(hv[t][0].x, hv[t][0].y), pack2(hv[t][0].z, hv[t][0].w),
                         pack2(hv[t][1].x, hv[t][1].y), pack2(hv[t][1].z, hv[t][1].w));
    *(uint4*)&As[(t & 1) * 8192 + w * 1024 + lane * 16] = q;   // lane-linear write
    __syncthreads();
    if (t < 3) loadB((t + 1) * 64, bfr[(t + 1) & 1]);
    bf16x8 af[2][4];                              // [kk][it], lane-linear reads
    #pragma unroll
    for (int kk = 0; kk < 2; kk++)
      #pragma unroll
      for (int it = 0; it < 4; it++)
        af[kk][it] = *(const bf16x8*)&As[(t & 1) * 8192 + (it * 2 + kk) * 1024 + lane * 16];
    #pragma unroll
    for (int kk = 0; kk < 2; kk++)
      #pragma unroll
      for (int it = 0; it < 4; it++)
        #pragma unroll
        for (int ot = 0; ot < 2; ot++)
          acc[it][ot] = __builtin_amdgcn_mfma_f32_16x16x32_bf16(af[kk][it], bfr[t & 1][ot * 2 + kk], acc[it][ot], 0, 0, 0);
  }

  // ---- epilogue 1: s1/s2 partial dots (log2e folded) ----
  float a1v[2], a2v[2];
  #pragma unroll
  for (int ot = 0; ot < 2; ot++){
    a1v[ot] = a[wc + ot * 16 + llo] * LOG2E;
    a2v[ot] = a[256 + wc + ot * 16 + llo] * LOG2E;
  }
  #pragma unroll
  for (int it = 0; it < 4; it++){
    #pragma unroll
    for (int q = 0; q < 4; q++){
      float p1 = acc[it][0][q] * a1v[0] + acc[it][1][q] * a1v[1];
      float p2 = acc[it][0][q] * a2v[0] + acc[it][1][q] * a2v[1];
      #pragma unroll
      for (int o = 1; o < 16; o <<= 1){ p1 += __shfl_xor(p1, o); p2 += __shfl_xor(p2, o); }
      if (llo == 0){
        s1p[w][it * 16 + lhi * 4 + q] = p1;
        s2p[w][it * 16 + lhi * 4 + q] = p2;
      }
    }
  }

  // ---- epilogue 2: transpose acc (bf16, round) into Ts[o][i_local] ----
  #pragma unroll
  for (int it = 0; it < 4; it++){
    #pragma unroll
    for (int ot = 0; ot < 2; ot++){
      int o = wc + ot * 16 + llo;
      uint2 u = make_uint2(pack2(acc[it][ot][0], acc[it][ot][1]),
                           pack2(acc[it][ot][2], acc[it][ot][3]));
      *(uint2*)&Ts[o * 72 + it * 16 + lhi * 4] = u;
    }
  }
  __syncthreads();

  if (tid < 64){
    float t1 = 0.f, t2 = 0.f;
    #pragma unroll
    for (int g = 0; g < 8; g++){ t1 += s1p[g][tid]; t2 += s2p[g][tid]; }
    s1c[r0 + tid] = t1;
    s2c[r0 + tid] = t2;
  }
  #pragma unroll
  for (int p = 0; p < 4; p++){
    int o = p * 64 + (tid >> 3), col = (tid & 7) * 8;
    *(uint4*)(WhT + (size_t)(b * 256 + o) * 2048 + i0 + col) = *(const uint4*)&Ts[o * 72 + col];
  }
}

// ---------------- K2: h' = softmax(P) @ Wh ----------------
// grid 256 (b=bid&7 XCD-affine), 512 threads. BM=64, BO=256, BK=64.
// FRAG-LINEAR Ps (conflict-free b128 LDS), one barrier/stage, static double
// buffering, P(t+1) VALU overlaps MFMA(t), bound-max one-pass softmax.
__global__ __launch_bounds__(512, 2) void k_attn(const float* __restrict__ s1c,
                                                 const float* __restrict__ s2c,
                                                 const unsigned short* __restrict__ WhT,
                                                 const unsigned long long* __restrict__ ab,
                                                 float* __restrict__ out){
  __shared__ __align__(16) float s2s[2048];                  //  8192 B
  __shared__ __align__(16) unsigned char PsB[2 * 8192];      // 16384 B
  __shared__ __align__(16) unsigned char bitsB[64 * 264];    // 16896 B
  __shared__ float s1s[64], lin[64], red[8], rsp[8][64];
  const int tid = threadIdx.x;
  const int bid = blockIdx.x;
  const int b = bid & 7, i0 = (bid >> 3) * 64;
  const int w = tid >> 6, lane = tid & 63, lhi = lane >> 4, llo = lane & 15;
  const int wc = w * 32;
  const int sit = w >> 1, skk = w & 1;           // P staging role: frag (sit,skk)
  const int prow = sit * 16 + llo;               // P row this thread computes

  // ---- preamble: stage s2 (+max), s1 tile, adjacency mask rows ----
  float4 v = ((const float4*)(s2c + (size_t)b * NN))[tid];
  ((float4*)s2s)[tid] = v;
  float vmax = fmaxf(fmaxf(v.x, v.y), fmaxf(v.z, v.w));
  #pragma unroll
  for (int o = 32; o; o >>= 1) vmax = fmaxf(vmax, __shfl_xor(vmax, o));
  if (lane == 0) red[w] = vmax;
  if (tid < 64) s1s[tid] = s1c[(size_t)b * NN + i0 + tid];
  #pragma unroll
  for (int k = 0; k < 4; k++){
    int g = k * 512 + tid;                       // 0..2047 mask words
    unsigned long long mw = ab[(size_t)i0 * 32 + g];
    *(unsigned long long*)&bitsB[(g >> 5) * 264 + (g & 31) * 8] = mw;
  }
  __syncthreads();
  float m2 = red[0];
  #pragma unroll
  for (int g = 1; g < 8; g++) m2 = fmaxf(m2, red[g]);

  const float s1v = s1s[prow];
  const float xm = s1v + m2;
  const float mv = fmaxf(xm, 0.2f * xm);         // upper bound on row max (lrelu monotone)
  const float c1 = s1v - mv;                     // y = max(s2+c1, 0.2*s2+c2)
  const float c2 = 0.2f * s1v - mv;
  float rs = 0.f;

  f32x4 acc[4][2];
  #pragma unroll
  for (int i = 0; i < 4; i++)
    #pragma unroll
    for (int j = 0; j < 2; j++){ acc[i][j][0]=0.f; acc[i][j][1]=0.f; acc[i][j][2]=0.f; acc[i][j][3]=0.f; }

  auto loadB = [&](int j0, bf16x8* dst){
    #pragma unroll
    for (int ot = 0; ot < 2; ot++)
      #pragma unroll
      for (int kk = 0; kk < 2; kk++)
        dst[ot * 2 + kk] = *(const bf16x8*)(WhT + (size_t)(b * 256 + wc + ot * 16 + llo) * 2048 + j0 + kk * 32 + lhi * 8);
  };

  unsigned puq[4];                               // packed 8 bf16 P values
  auto computeP = [&](int tn){
    unsigned bits = bitsB[prow * 264 + tn * 8 + skk * 4 + lhi];
    const float* sp = &s2s[tn * 64 + skk * 32 + lhi * 8];
    float4 xa = *(const float4*)sp;
    float4 xb = *(const float4*)(sp + 4);
    float xs[8] = {xa.x, xa.y, xa.z, xa.w, xb.x, xb.y, xb.z, xb.w};
    unsigned pu[8];
    #pragma unroll
    for (int e = 0; e < 8; e++){
      float s2v = xs[e];
      float y = fmaxf(s2v + c1, __builtin_fmaf(0.2f, s2v, c2));
      float p = __builtin_amdgcn_exp2f(y);
      unsigned m = ((bits >> e) & 1u) ? 0xFFFF0000u : 0u;
      unsigned u = __float_as_uint(p) & m;
      rs += __uint_as_float(u);
      pu[e] = u;
    }
    puq[0] = permpack(pu[1], pu[0]); puq[1] = permpack(pu[3], pu[2]);
    puq[2] = permpack(pu[5], pu[4]); puq[3] = permpack(pu[7], pu[6]);
  };

  // stage body: compile-time BUF, static B-frag arrays (R4 spill lesson)
  auto stageBody = [&](int t, int BUF, bf16x8* curB, bf16x8* nxtB, bool last){
    *(uint4*)&PsB[BUF * 8192 + w * 1024 + lane * 16] = *(uint4*)&puq[0];   // lane-linear
    __syncthreads();
    if (!last) loadB((t + 1) * 64, nxtB);
    bf16x8 af[2][4];                             // [kk][it], lane-linear reads
    #pragma unroll
    for (int kk = 0; kk < 2; kk++)
      #pragma unroll
      for (int it = 0; it < 4; it++)
        af[kk][it] = *(const bf16x8*)&PsB[BUF * 8192 + (it * 2 + kk) * 1024 + lane * 16];
    if (!last) computeP(t + 1);                  // VALU overlaps MFMA below
    #pragma unroll
    for (int kk = 0; kk < 2; kk++)
      #pragma unroll
      for (int it = 0; it < 4; it++)
        #pragma unroll
        for (int ot = 0; ot < 2; ot++)
          acc[it][ot] = __builtin_amdgcn_mfma_f32_16x16x32_bf16(af[kk][it], curB[ot * 2 + kk], acc[it][ot], 0, 0, 0);
  };

  bf16x8 bA[4], bB[4];
  loadB(0, bA);
  computeP(0);
  for (int t2 = 0; t2 < 32; t2 += 2){
    stageBody(t2,     0, bA, bB, false);
    stageBody(t2 + 1, 1, bB, bA, t2 + 1 == 31);
  }

  // ---- row sums: reduce over lhi in-wave, then over wave pair via LDS ----
  rs += __shfl_xor(rs, 16);
  rs += __shfl_xor(rs, 32);
  if (lhi == 0) rsp[w][prow] = rs;
  __syncthreads();
  if (tid < 64){
    int it = tid >> 4;
    lin[tid] = 1.0f / (rsp[it * 2][tid] + rsp[it * 2 + 1][tid]);
  }
  __syncthreads();

  // ---- epilogue: scale + store ----
  #pragma unroll
  for (int it = 0; it < 4; it++){
    #pragma unroll
    for (int ot = 0; ot < 2; ot++){
      int col = wc + ot * 16 + llo;
      #pragma unroll
      for (int q = 0; q < 4; q++){
        int row = it * 16 + lhi * 4 + q;
        out[(size_t)(b * NN + i0 + row) * 256 + col] = acc[it][ot][q] * lin[row];
      }
    }
  }
}

extern "C" void kernel_launch(void* const* d_in, const int* in_sizes, int n_in,
                              void* d_out, int out_size, void* d_ws, size_t ws_size,
                              hipStream_t stream) {
  const float* h   = (const float*)d_in[0];
  const float* adj = (const float*)d_in[1];
  const float* W   = (const float*)d_in[2];
  const float* a   = (const float*)d_in[3];
  float* out = (float*)d_out;

  char* ws = (char*)d_ws;
  unsigned short* WhT      = (unsigned short*)(ws);                 // 8,388,608 B
  unsigned short* Wt       = (unsigned short*)(ws + 8388608);       //   131,072 B
  unsigned long long* ab   = (unsigned long long*)(ws + 8519680);   //   524,288 B
  float* s1c               = (float*)(ws + 9043968);                //    65,536 B
  float* s2c               = (float*)(ws + 9109504);                //    65,536 B

  hipLaunchKernelGGL(k_prep,       dim3(2304), dim3(256), 0, stream, adj, W, ab, Wt);
  hipLaunchKernelGGL(k_fused_gemm, dim3(256),  dim3(512), 0, stream, h, Wt, a, WhT, s1c, s2c);
  hipLaunchKernelGGL(k_attn,       dim3(256),  dim3(512), 0, stream, s1c, s2c, WhT, ab, out);
}